// Round 1
// baseline (119.605 us; speedup 1.0000x reference)
//
#include <hip/hip_runtime.h>

// Problem constants (from reference):
//   events: (8, 32, 65536) f32   pos: (1, 32, 1024) f32
//   out[b,c,t] = events[b,c,t-d_c] if t >= d_c else 0, d_c = argmax_j pos[c,j] * 64
#define N_SAMPLES 65536
#define POS_LEN   1024
#define STEP      64          // N_SAMPLES / POS_LEN
#define NCH       32
#define NB        8
#define ROW4      (N_SAMPLES / 4)   // 16384 float4 per row

// One wave (64 lanes) per channel: first-occurrence argmax over 1024 floats.
__global__ void argmax_kernel(const float* __restrict__ pos, int* __restrict__ delay) {
    const int c    = blockIdx.x;       // 0..31
    const int lane = threadIdx.x;      // 0..63
    const float* row = pos + c * POS_LEN;

    float best = -__builtin_inff();
    int   bidx = POS_LEN;              // sentinel (never wins ties)
    // strided coalesced scan; strict '>' keeps earliest index within lane
    for (int k = lane; k < POS_LEN; k += 64) {
        float v = row[k];
        if (v > best) { best = v; bidx = k; }
    }
    // 64-lane butterfly-ish reduce; tie-break to lower index = first occurrence
    for (int off = 32; off > 0; off >>= 1) {
        float ov = __shfl_down(best, off, 64);
        int   oi = __shfl_down(bidx, off, 64);
        if (ov > best || (ov == best && oi < bidx)) { best = ov; bidx = oi; }
    }
    if (lane == 0) delay[c] = bidx * STEP;   // delay in float elements (multiple of 64)
}

// Grid-stride float4 shifted copy. d_c % 64 == 0 so float4 alignment holds.
__global__ void shift_kernel(const float4* __restrict__ in, float4* __restrict__ out,
                             const int* __restrict__ delay) {
    __shared__ int sdelay4[NCH];
    if (threadIdx.x < NCH) sdelay4[threadIdx.x] = delay[threadIdx.x] >> 2;
    __syncthreads();

    const int total  = NB * NCH * ROW4;             // 4,194,304 float4
    const int stride = gridDim.x * blockDim.x;
    for (int i = blockIdx.x * blockDim.x + threadIdx.x; i < total; i += stride) {
        const int t4 = i & (ROW4 - 1);              // position within row (float4 units)
        const int c  = (i >> 14) & (NCH - 1);       // channel
        const int d4 = sdelay4[c];
        float4 v;
        if (t4 >= d4) {
            v = in[i - d4];                         // same row, shifted
        } else {
            v = make_float4(0.f, 0.f, 0.f, 0.f);
        }
        out[i] = v;
    }
}

extern "C" void kernel_launch(void* const* d_in, const int* in_sizes, int n_in,
                              void* d_out, int out_size, void* d_ws, size_t ws_size,
                              hipStream_t stream) {
    const float* events = (const float*)d_in[0];   // (8,32,65536)
    const float* pos    = (const float*)d_in[1];   // (1,32,1024)
    float*       out    = (float*)d_out;           // (8,32,65536)
    int*         delay  = (int*)d_ws;              // 32 ints of scratch

    argmax_kernel<<<NCH, 64, 0, stream>>>(pos, delay);

    // memory-bound streaming: ~2048 blocks, grid-stride the rest (G11)
    shift_kernel<<<2048, 256, 0, stream>>>((const float4*)events, (float4*)out, delay);
}

// Round 7
// 118.922 us; speedup vs baseline: 1.0057x; 1.0057x over previous
//
#include <hip/hip_runtime.h>

// out[b,c,t] = events[b,c,t-d_c] if t >= d_c else 0
// d_c = argmax_j(pos[c,j]) * 64   (first occurrence; softmax is monotone)
#define N_SAMPLES 65536
#define POS_LEN   1024
#define STEP      64
#define NCH       32
#define NB        8
#define ROW4      (N_SAMPLES / 4)    // 16384 float4 per row
#define SEGS      8                  // blocks per row
#define SEG4      (ROW4 / SEGS)      // 2048 float4 per block

typedef float f32x4 __attribute__((ext_vector_type(4)));

// One block = one (row, segment). Block prologue computes its channel's argmax
// (4 KB from L2), then streams its 32 KiB segment with nontemporal ld/st.
__global__ __launch_bounds__(256) void dirac_shift(const float* __restrict__ pos,
                                                   const f32x4* __restrict__ in,
                                                   f32x4* __restrict__ out) {
    const int g   = blockIdx.x;           // 0..2047
    const int row = g >> 3;               // 0..255  (= b*32 + c)
    const int seg = g & (SEGS - 1);
    const int c   = row & (NCH - 1);
    const int tid = threadIdx.x;          // 0..255

    // ---- per-block argmax over pos[c][0..1023], first-occurrence tie-break ----
    __shared__ float swv[4];
    __shared__ int   swi[4];
    __shared__ int   sd4;

    {
        const f32x4 v = ((const f32x4*)(pos + c * POS_LEN))[tid];  // 256 threads x 4 floats
        float best = v[0];
        int   bidx = tid * 4;
        #pragma unroll
        for (int j = 1; j < 4; ++j) {
            if (v[j] > best) { best = v[j]; bidx = tid * 4 + j; }
        }
        // wave-64 reduce, prefer lower index on ties
        #pragma unroll
        for (int off = 32; off > 0; off >>= 1) {
            float ov = __shfl_down(best, off, 64);
            int   oi = __shfl_down(bidx, off, 64);
            if (ov > best || (ov == best && oi < bidx)) { best = ov; bidx = oi; }
        }
        const int lane = tid & 63, wave = tid >> 6;
        if (lane == 0) { swv[wave] = best; swi[wave] = bidx; }
    }
    __syncthreads();
    if (tid == 0) {
        float best = swv[0];
        int   bidx = swi[0];
        #pragma unroll
        for (int w = 1; w < 4; ++w) {
            if (swv[w] > best || (swv[w] == best && swi[w] < bidx)) { best = swv[w]; bidx = swi[w]; }
        }
        sd4 = bidx * (STEP / 4);          // delay in float4 units (multiple of 16)
    }
    __syncthreads();

    // ---- streaming shifted copy of this block's segment ----
    const int d4 = sd4;
    const f32x4* inrow  = in  + (size_t)row * ROW4;
    f32x4*       outrow = out + (size_t)row * ROW4;
    const int base = seg * SEG4;

    #pragma unroll
    for (int k = 0; k < SEG4 / 256; ++k) {       // 8 iterations
        const int t4 = base + k * 256 + tid;
        f32x4 v = {0.f, 0.f, 0.f, 0.f};
        if (t4 >= d4) v = __builtin_nontemporal_load(inrow + (t4 - d4));
        __builtin_nontemporal_store(v, outrow + t4);
    }
}

extern "C" void kernel_launch(void* const* d_in, const int* in_sizes, int n_in,
                              void* d_out, int out_size, void* d_ws, size_t ws_size,
                              hipStream_t stream) {
    const float* events = (const float*)d_in[0];   // (8,32,65536)
    const float* pos    = (const float*)d_in[1];   // (1,32,1024)
    float*       out    = (float*)d_out;           // (8,32,65536)

    dirac_shift<<<NB * NCH * SEGS, 256, 0, stream>>>(pos, (const f32x4*)events, (f32x4*)out);
}

// Round 10
// 114.051 us; speedup vs baseline: 1.0487x; 1.0427x over previous
//
#include <hip/hip_runtime.h>

// out[b,c,t] = events[b,c,t-d_c] if t >= d_c else 0
// d_c = argmax_j(pos[c,j]) * 64   (first occurrence; softmax is monotone)
#define N_SAMPLES 65536
#define POS_LEN   1024
#define STEP      64
#define NCH       32
#define NB        8
#define ROW4      (N_SAMPLES / 4)    // 16384 float4 per row
#define SEGS      8                  // blocks per row
#define SEG4      (ROW4 / SEGS)      // 2048 float4 per block

typedef float f32x4 __attribute__((ext_vector_type(4)));

// One block = one (row, segment). Block prologue computes its channel's argmax
// (4 KB from L2), then streams its 32 KiB segment: zero-fill region and copy
// region as separate branch-free loops, plain (cached) ld/st — m13's 6.29 TB/s
// ceiling was a plain float4 copy; nt hints measured neutral-to-negative (R7).
__global__ __launch_bounds__(256) void dirac_shift(const float* __restrict__ pos,
                                                   const f32x4* __restrict__ in,
                                                   f32x4* __restrict__ out) {
    const int g   = blockIdx.x;           // 0..2047
    const int row = g >> 3;               // 0..255  (= b*32 + c)
    const int seg = g & (SEGS - 1);
    const int c   = row & (NCH - 1);
    const int tid = threadIdx.x;          // 0..255

    // ---- per-block argmax over pos[c][0..1023], first-occurrence tie-break ----
    __shared__ float swv[4];
    __shared__ int   swi[4];
    __shared__ int   sd4;

    {
        const f32x4 v = ((const f32x4*)(pos + c * POS_LEN))[tid];  // 256 threads x 4 floats
        float best = v[0];
        int   bidx = tid * 4;
        #pragma unroll
        for (int j = 1; j < 4; ++j) {
            if (v[j] > best) { best = v[j]; bidx = tid * 4 + j; }
        }
        // wave-64 reduce, prefer lower index on ties
        #pragma unroll
        for (int off = 32; off > 0; off >>= 1) {
            float ov = __shfl_down(best, off, 64);
            int   oi = __shfl_down(bidx, off, 64);
            if (ov > best || (ov == best && oi < bidx)) { best = ov; bidx = oi; }
        }
        const int lane = tid & 63, wave = tid >> 6;
        if (lane == 0) { swv[wave] = best; swi[wave] = bidx; }
    }
    __syncthreads();
    if (tid == 0) {
        float best = swv[0];
        int   bidx = swi[0];
        #pragma unroll
        for (int w = 1; w < 4; ++w) {
            if (swv[w] > best || (swv[w] == best && swi[w] < bidx)) { best = swv[w]; bidx = swi[w]; }
        }
        sd4 = bidx * (STEP / 4);          // delay in float4 units (multiple of 16)
    }
    __syncthreads();

    // ---- streaming shifted copy of this block's segment, split loops ----
    const int d4   = sd4;
    const int base = seg * SEG4;
    const int end  = base + SEG4;
    const f32x4* inrow  = in  + (size_t)row * ROW4;
    f32x4*       outrow = out + (size_t)row * ROW4;

    // zero-fill [base, min(end, d4))
    const int zhi = d4 < end ? d4 : end;
    const f32x4 zero = {0.f, 0.f, 0.f, 0.f};
    for (int t4 = base + tid; t4 < zhi; t4 += 256) {
        outrow[t4] = zero;
    }

    // copy [max(base, d4), end):  out[t4] = in[t4 - d4]
    const int clo = d4 > base ? d4 : base;
    #pragma unroll 4
    for (int t4 = clo + tid; t4 < end; t4 += 256) {
        outrow[t4] = inrow[t4 - d4];
    }
}

extern "C" void kernel_launch(void* const* d_in, const int* in_sizes, int n_in,
                              void* d_out, int out_size, void* d_ws, size_t ws_size,
                              hipStream_t stream) {
    const float* events = (const float*)d_in[0];   // (8,32,65536)
    const float* pos    = (const float*)d_in[1];   // (1,32,1024)
    float*       out    = (float*)d_out;           // (8,32,65536)

    dirac_shift<<<NB * NCH * SEGS, 256, 0, stream>>>(pos, (const f32x4*)events, (f32x4*)out);
}